// Round 1
// baseline (947.759 us; speedup 1.0000x reference)
//
#include <hip/hip_runtime.h>

typedef __bf16 bf16;
typedef __bf16 bf16x8 __attribute__((ext_vector_type(8)));
typedef __bf16 bf16x4 __attribute__((ext_vector_type(4)));
typedef float f32x4 __attribute__((ext_vector_type(4)));

#define MFMA16(a, b, c) __builtin_amdgcn_mfma_f32_16x16x32_bf16(a, b, c, 0, 0, 0)

// Problem constants
#define Bq 2
#define Sq 2048
#define Eq 2048
#define Hq 16
#define Dq 128
#define N3E 6144

__device__ __forceinline__ bf16 f2bf(float f) {
  unsigned u = __builtin_bit_cast(unsigned, f);
  u += 0x7FFFu + ((u >> 16) & 1u);
  unsigned short h = (unsigned short)(u >> 16);
  return __builtin_bit_cast(bf16, h);
}
__device__ __forceinline__ float bf2f(bf16 b) {
  unsigned short h = __builtin_bit_cast(unsigned short, b);
  return __builtin_bit_cast(float, (unsigned)h << 16);
}
__device__ __forceinline__ float rowmax16(float v) {
  v = fmaxf(v, __shfl_xor(v, 1, 64));
  v = fmaxf(v, __shfl_xor(v, 2, 64));
  v = fmaxf(v, __shfl_xor(v, 4, 64));
  v = fmaxf(v, __shfl_xor(v, 8, 64));
  return v;
}
__device__ __forceinline__ float rowsum16(float v) {
  v += __shfl_xor(v, 1, 64);
  v += __shfl_xor(v, 2, 64);
  v += __shfl_xor(v, 4, 64);
  v += __shfl_xor(v, 8, 64);
  return v;
}

// ---------------------------------------------------------------------------
// Kernel 1: qkv = x @ W_qkv  (fp32 in, bf16 MFMA, bf16 out)
// Writes q,k as [b,h,s,d]; v transposed as [b,h,d,s] (for PV B-fragments).
// Tile 128x128, BK=64, 256 threads (4 waves, 2x2 of 64x64 each).
// ---------------------------------------------------------------------------
__global__ __launch_bounds__(256) void gemm_qkv(
    const float* __restrict__ x, const float* __restrict__ w,
    bf16* __restrict__ qws, bf16* __restrict__ kws, bf16* __restrict__ vtws) {
  __shared__ __align__(16) bf16 Ald[128][72];  // [m][k], pad 64->72
  __shared__ __align__(16) bf16 Bld[128][72];  // [n][k] (transposed), pad

  const int tid = threadIdx.x;
  const int lane = tid & 63, wave = tid >> 6;
  const int q4 = lane >> 4, c = lane & 15;
  const int m0 = blockIdx.y * 128, n0 = blockIdx.x * 128;
  const int wm = (wave >> 1) * 64, wn = (wave & 1) * 64;

  f32x4 acc[4][4];
#pragma unroll
  for (int i = 0; i < 4; ++i)
#pragma unroll
    for (int j = 0; j < 4; ++j) acc[i][j] = {0.f, 0.f, 0.f, 0.f};

  for (int k0 = 0; k0 < Eq; k0 += 64) {
    // stage A: x[m0..m0+128)[k0..k0+64)  fp32 -> bf16
    {
      const int row = tid >> 4, k4 = (tid & 15) << 2;
      const float* gp = x + (size_t)(m0 + row) * Eq + k0 + k4;
#pragma unroll
      for (int p = 0; p < 8; ++p) {
        float4 v = *(const float4*)(gp + (size_t)p * 16 * Eq);
        bf16* dst = &Ald[row + p * 16][k4];
        dst[0] = f2bf(v.x); dst[1] = f2bf(v.y);
        dst[2] = f2bf(v.z); dst[3] = f2bf(v.w);
      }
    }
    // stage B transposed: W[k0..k0+64)[n0..n0+128) -> Bld[n][k]
    {
      const int krow = tid >> 5, n4 = (tid & 31) << 2;
      const float* gp = w + (size_t)(k0 + krow) * N3E + n0 + n4;
#pragma unroll
      for (int p = 0; p < 8; ++p) {
        float4 v = *(const float4*)(gp + (size_t)p * 8 * N3E);
        Bld[n4 + 0][krow + p * 8] = f2bf(v.x);
        Bld[n4 + 1][krow + p * 8] = f2bf(v.y);
        Bld[n4 + 2][krow + p * 8] = f2bf(v.z);
        Bld[n4 + 3][krow + p * 8] = f2bf(v.w);
      }
    }
    __syncthreads();
#pragma unroll
    for (int kk = 0; kk < 64; kk += 32) {
      bf16x8 af[4], bf[4];
#pragma unroll
      for (int i = 0; i < 4; ++i)
        af[i] = *(const bf16x8*)&Ald[wm + i * 16 + c][kk + q4 * 8];
#pragma unroll
      for (int j = 0; j < 4; ++j)
        bf[j] = *(const bf16x8*)&Bld[wn + j * 16 + c][kk + q4 * 8];
#pragma unroll
      for (int i = 0; i < 4; ++i)
#pragma unroll
        for (int j = 0; j < 4; ++j)
          acc[i][j] = MFMA16(af[i], bf[j], acc[i][j]);
    }
    __syncthreads();
  }

  // epilogue: scatter into q/k ([b,h,s,d]) or v-transposed ([b,h,d,s])
#pragma unroll
  for (int i = 0; i < 4; ++i) {
    const int row_base = m0 + wm + i * 16 + q4 * 4;  // 4 consecutive rows rr
    const int b = row_base >> 11, s0 = row_base & 2047;
#pragma unroll
    for (int j = 0; j < 4; ++j) {
      const int colg = n0 + wn + j * 16 + c;
      const int t = colg >> 11, cw = colg & 2047;
      const int h = cw >> 7, d = cw & 127;
      if (t == 2) {
        bf16x4 pv;
        pv[0] = f2bf(acc[i][j][0]); pv[1] = f2bf(acc[i][j][1]);
        pv[2] = f2bf(acc[i][j][2]); pv[3] = f2bf(acc[i][j][3]);
        size_t idx = (((size_t)(b * Hq + h) * Dq + d) * Sq + s0);
        *(bf16x4*)&vtws[idx] = pv;
      } else {
        bf16* dst = (t == 0) ? qws : kws;
        size_t base = ((size_t)(b * Hq + h) * Sq + s0) * Dq + d;
#pragma unroll
        for (int rr = 0; rr < 4; ++rr)
          dst[base + (size_t)rr * Dq] = f2bf(acc[i][j][rr]);
      }
    }
  }
}

// ---------------------------------------------------------------------------
// Kernel 2: in-place RoPE on q,k  [b,h,s,d] bf16
// ---------------------------------------------------------------------------
__global__ __launch_bounds__(256) void rope_kernel(bf16* __restrict__ qws,
                                                   bf16* __restrict__ kws) {
  const int idx = blockIdx.x * 256 + threadIdx.x;  // 2 * 2^22
  const int t = idx >> 22;
  const int r = idx & ((1 << 22) - 1);
  const int j = r & 63;
  const int bhs = r >> 6;
  const int s = bhs & (Sq - 1);
  bf16* p = (t == 0) ? qws : kws;
  const size_t base = (size_t)bhs * Dq;
  // inv_freq = 10000^(-j/64) = exp(-j * ln(10000)/64)
  const float freq = __expf(-(float)j * 0.14391157f);
  const float ang = (float)s * freq;
  float sv, cv;
  __sincosf(ang, &sv, &cv);
  const float x1 = bf2f(p[base + j]);
  const float x2 = bf2f(p[base + 64 + j]);
  p[base + j] = f2bf(x1 * cv - x2 * sv);
  p[base + 64 + j] = f2bf(x2 * cv + x1 * sv);
}

// ---------------------------------------------------------------------------
// Kernel 3: flash attention. Block = (qb, h, b), 256 thr = 4 waves.
// Wave owns 32 q-rows; K/V chunks of 128 read directly from global
// (B-fragments are contiguous 16B thanks to k [b,h,s,d] / vt [b,h,d,s]).
// P goes C-layout -> LDS -> A-layout (m120 pattern).
// ---------------------------------------------------------------------------
__global__ __launch_bounds__(256) void attn_kernel(
    const bf16* __restrict__ qws, const bf16* __restrict__ kws,
    const bf16* __restrict__ vtws, float* __restrict__ out) {
  __shared__ __align__(16) bf16 Plds[4][32][136];

  const int tid = threadIdx.x, lane = tid & 63, wave = tid >> 6;
  const int q4 = lane >> 4, c = lane & 15;
  const int qb = blockIdx.x, h = blockIdx.y, b = blockIdx.z;
  const size_t bh = (size_t)(b * Hq + h);
  const bf16* qbase = qws + bh * Sq * Dq;
  const bf16* kbase = kws + bh * Sq * Dq;
  const bf16* vbase = vtws + bh * Dq * Sq;
  const int wq = wave * 32;
  const float scale = 0.08838834764831845f;  // 1/sqrt(128)

  // preload Q fragments (A-layout: m=c, k=q4*8.. , 4 k-steps of 32)
  bf16x8 qf[2][4];
#pragma unroll
  for (int i = 0; i < 2; ++i)
#pragma unroll
    for (int ks = 0; ks < 4; ++ks)
      qf[i][ks] = *(const bf16x8*)
          &qbase[(size_t)(qb * 128 + wq + i * 16 + c) * Dq + ks * 32 + q4 * 8];

  f32x4 O[2][8];
  float m_i[2][4], l_i[2][4];
#pragma unroll
  for (int i = 0; i < 2; ++i) {
#pragma unroll
    for (int j = 0; j < 8; ++j) O[i][j] = {0.f, 0.f, 0.f, 0.f};
#pragma unroll
    for (int rr = 0; rr < 4; ++rr) { m_i[i][rr] = -1e30f; l_i[i][rr] = 0.f; }
  }

  for (int kb = 0; kb <= qb; ++kb) {
    // ---- scores = Q K^T ----
    f32x4 sc[2][8];
#pragma unroll
    for (int i = 0; i < 2; ++i)
#pragma unroll
      for (int j = 0; j < 8; ++j) sc[i][j] = {0.f, 0.f, 0.f, 0.f};
    const bf16* kchunk = kbase + (size_t)kb * 128 * Dq;
#pragma unroll
    for (int ks = 0; ks < 4; ++ks) {
#pragma unroll
      for (int j = 0; j < 8; ++j) {
        bf16x8 bk = *(const bf16x8*)
            &kchunk[(size_t)(j * 16 + c) * Dq + ks * 32 + q4 * 8];
        sc[0][j] = MFMA16(qf[0][ks], bk, sc[0][j]);
        sc[1][j] = MFMA16(qf[1][ks], bk, sc[1][j]);
      }
    }
    // ---- scale, causal mask, online softmax ----
    const bool diag = (kb == qb);
#pragma unroll
    for (int i = 0; i < 2; ++i) {
#pragma unroll
      for (int rr = 0; rr < 4; ++rr) {
        const int lq = wq + i * 16 + q4 * 4 + rr;
        float m = -1e30f;
#pragma unroll
        for (int j = 0; j < 8; ++j) {
          float v = sc[i][j][rr] * scale;
          if (diag && (j * 16 + c) > lq) v = -1e30f;
          sc[i][j][rr] = v;
          m = fmaxf(m, v);
        }
        m = rowmax16(m);
        const float mn = fmaxf(m_i[i][rr], m);
        const float alpha = __expf(m_i[i][rr] - mn);
        m_i[i][rr] = mn;
        float s = 0.f;
#pragma unroll
        for (int j = 0; j < 8; ++j) {
          float p = __expf(sc[i][j][rr] - mn);
          sc[i][j][rr] = p;
          s += p;
        }
        s = rowsum16(s);
        l_i[i][rr] = l_i[i][rr] * alpha + s;
#pragma unroll
        for (int jd = 0; jd < 8; ++jd) O[i][jd][rr] *= alpha;
      }
    }
    // ---- P: C-layout -> LDS (per-wave region) ----
#pragma unroll
    for (int i = 0; i < 2; ++i)
#pragma unroll
      for (int j = 0; j < 8; ++j)
#pragma unroll
        for (int rr = 0; rr < 4; ++rr)
          Plds[wave][i * 16 + q4 * 4 + rr][j * 16 + c] = f2bf(sc[i][j][rr]);
    __syncthreads();
    // ---- O += P V ----
#pragma unroll
    for (int j2 = 0; j2 < 4; ++j2) {
      bf16x8 ap0 = *(const bf16x8*)&Plds[wave][c][j2 * 32 + q4 * 8];
      bf16x8 ap1 = *(const bf16x8*)&Plds[wave][16 + c][j2 * 32 + q4 * 8];
#pragma unroll
      for (int j = 0; j < 8; ++j) {
        bf16x8 bv = *(const bf16x8*)
            &vbase[(size_t)(j * 16 + c) * Sq + kb * 128 + j2 * 32 + q4 * 8];
        O[0][j] = MFMA16(ap0, bv, O[0][j]);
        O[1][j] = MFMA16(ap1, bv, O[1][j]);
      }
    }
    __syncthreads();
  }

  // ---- epilogue: out[b][s][h*128+d] fp32 ----
#pragma unroll
  for (int i = 0; i < 2; ++i)
#pragma unroll
    for (int rr = 0; rr < 4; ++rr) {
      const float inv = 1.0f / l_i[i][rr];
      const int s = qb * 128 + wq + i * 16 + q4 * 4 + rr;
      float* orow = out + ((size_t)b * Sq + s) * Eq + h * Dq;
#pragma unroll
      for (int j = 0; j < 8; ++j) orow[j * 16 + c] = O[i][j][rr] * inv;
    }
}

// ---------------------------------------------------------------------------
extern "C" void kernel_launch(void* const* d_in, const int* in_sizes, int n_in,
                              void* d_out, int out_size, void* d_ws,
                              size_t ws_size, hipStream_t stream) {
  const float* x = (const float*)d_in[0];
  // d_in[1] = mask (causal tril) — implemented analytically, not read.
  const float* w = (const float*)d_in[2];
  float* out = (float*)d_out;

  const size_t perT = (size_t)Bq * Hq * Sq * Dq;  // 8,388,608 elems
  bf16* qws = (bf16*)d_ws;
  bf16* kws = qws + perT;
  bf16* vtws = kws + perT;

  dim3 g1(N3E / 128, (Bq * Sq) / 128);  // 48 x 32
  gemm_qkv<<<g1, 256, 0, stream>>>(x, w, qws, kws, vtws);

  rope_kernel<<<(2u * Bq * Hq * Sq * 64) / 256, 256, 0, stream>>>(qws, kws);

  dim3 g3(Sq / 128, Hq, Bq);  // 16 x 16 x 2
  attn_kernel<<<g3, 256, 0, stream>>>(qws, kws, vtws, out);
}

// Round 2
// 687.136 us; speedup vs baseline: 1.3793x; 1.3793x over previous
//
#include <hip/hip_runtime.h>

typedef __bf16 bf16;
typedef __bf16 bf16x8 __attribute__((ext_vector_type(8)));
typedef __bf16 bf16x4 __attribute__((ext_vector_type(4)));
typedef float f32x4 __attribute__((ext_vector_type(4)));

#define MFMA16(a, b, c) __builtin_amdgcn_mfma_f32_16x16x32_bf16(a, b, c, 0, 0, 0)

// Problem constants
#define Bq 2
#define Sq 2048
#define Eq 2048
#define Hq 16
#define Dq 128
#define N3E 6144

#define GLOAD_LDS16(gp, lp) \
  __builtin_amdgcn_global_load_lds( \
      (const __attribute__((address_space(1))) void*)(gp), \
      (__attribute__((address_space(3))) void*)(lp), 16, 0, 0)

__device__ __forceinline__ bf16 f2bf(float f) {
  unsigned u = __builtin_bit_cast(unsigned, f);
  u += 0x7FFFu + ((u >> 16) & 1u);
  unsigned short h = (unsigned short)(u >> 16);
  return __builtin_bit_cast(bf16, h);
}
__device__ __forceinline__ float bf2f(bf16 b) {
  unsigned short h = __builtin_bit_cast(unsigned short, b);
  return __builtin_bit_cast(float, (unsigned)h << 16);
}
__device__ __forceinline__ float rowmax16(float v) {
  v = fmaxf(v, __shfl_xor(v, 1, 64));
  v = fmaxf(v, __shfl_xor(v, 2, 64));
  v = fmaxf(v, __shfl_xor(v, 4, 64));
  v = fmaxf(v, __shfl_xor(v, 8, 64));
  return v;
}
__device__ __forceinline__ float rowsum16(float v) {
  v += __shfl_xor(v, 1, 64);
  v += __shfl_xor(v, 2, 64);
  v += __shfl_xor(v, 4, 64);
  v += __shfl_xor(v, 8, 64);
  return v;
}

// ---------------------------------------------------------------------------
// Kernel 0a: x fp32 -> xb bf16 (elementwise, 8 elems/thread)
// ---------------------------------------------------------------------------
__global__ __launch_bounds__(256) void convert_x(const float* __restrict__ x,
                                                 bf16* __restrict__ xb) {
  const size_t i = ((size_t)blockIdx.x * 256 + threadIdx.x) * 8;
  float4 a = *(const float4*)(x + i);
  float4 b = *(const float4*)(x + i + 4);
  bf16x8 o;
  o[0] = f2bf(a.x); o[1] = f2bf(a.y); o[2] = f2bf(a.z); o[3] = f2bf(a.w);
  o[4] = f2bf(b.x); o[5] = f2bf(b.y); o[6] = f2bf(b.z); o[7] = f2bf(b.w);
  *(bf16x8*)(xb + i) = o;
}

// ---------------------------------------------------------------------------
// Kernel 0b: W fp32 [k][n] -> wt bf16 [n][k] (64x64 LDS tile transpose)
// ---------------------------------------------------------------------------
__global__ __launch_bounds__(256) void convert_wt(const float* __restrict__ w,
                                                  bf16* __restrict__ wt) {
  __shared__ __align__(16) bf16 T[64][72];
  const int tid = threadIdx.x;
  const int kb = blockIdx.x & 31;  // 2048/64
  const int nb = blockIdx.x >> 5;  // 6144/64
  const int k0 = kb * 64, n0 = nb * 64;
  {
    const int kr = tid >> 4, nc = (tid & 15) * 4;
#pragma unroll
    for (int p = 0; p < 4; ++p) {
      const int k = kr + p * 16;
      float4 v = *(const float4*)(w + (size_t)(k0 + k) * N3E + n0 + nc);
      T[nc + 0][k] = f2bf(v.x);
      T[nc + 1][k] = f2bf(v.y);
      T[nc + 2][k] = f2bf(v.z);
      T[nc + 3][k] = f2bf(v.w);
    }
  }
  __syncthreads();
#pragma unroll
  for (int q = 0; q < 2; ++q) {
    const int id = q * 256 + tid;
    const int n = id >> 3, ch = id & 7;
    bf16x8 v = *(const bf16x8*)&T[n][ch * 8];
    *(bf16x8*)(wt + (size_t)(n0 + n) * Eq + k0 + ch * 8) = v;
  }
}

// ---------------------------------------------------------------------------
// Kernel 1: qkv = xb @ wt^T (both k-major bf16), m97-style.
// Tile 128x128, BK=64, 256 thr. Staging via global_load_lds width=16.
// LDS chunk-major: slot = kchunk*128 + row (16B slots) -> conflict-light
// ds_read_b128 (bank = 4*(row%8), 2-way alias only).
// Writes q,k as [b,h,s,d]; v transposed as [b,h,d,s].
// ---------------------------------------------------------------------------
__global__ __launch_bounds__(256) void gemm_qkv(
    const bf16* __restrict__ xb, const bf16* __restrict__ wt,
    bf16* __restrict__ qws, bf16* __restrict__ kws, bf16* __restrict__ vtws) {
  __shared__ __align__(16) bf16 Ald[1024 * 8];  // 16 KB: [chunk(8)][row(128)][8]
  __shared__ __align__(16) bf16 Bld[1024 * 8];  // 16 KB

  const int tid = threadIdx.x;
  const int lane = tid & 63, wave = tid >> 6;
  const int q4 = lane >> 4, c = lane & 15;
  const int m0 = blockIdx.y * 128, n0 = blockIdx.x * 128;
  const int wm = (wave >> 1) * 64, wn = (wave & 1) * 64;

  f32x4 acc[4][4];
#pragma unroll
  for (int i = 0; i < 4; ++i)
#pragma unroll
    for (int j = 0; j < 4; ++j) acc[i][j] = {0.f, 0.f, 0.f, 0.f};

  for (int k0 = 0; k0 < Eq; k0 += 64) {
    // ---- DMA staging: 1024 slots A + 1024 slots B, 16B each ----
#pragma unroll
    for (int it = 0; it < 4; ++it) {
      const int slot = it * 256 + tid;
      const int chunk = slot >> 7, row = slot & 127;
      const bf16* gp = xb + (size_t)(m0 + row) * Eq + k0 + chunk * 8;
      GLOAD_LDS16(gp, Ald + slot * 8);
    }
#pragma unroll
    for (int it = 0; it < 4; ++it) {
      const int slot = it * 256 + tid;
      const int chunk = slot >> 7, row = slot & 127;
      const bf16* gp = wt + (size_t)(n0 + row) * Eq + k0 + chunk * 8;
      GLOAD_LDS16(gp, Bld + slot * 8);
    }
    __syncthreads();  // drains vmcnt: tiles visible
    // ---- compute ----
#pragma unroll
    for (int kk = 0; kk < 64; kk += 32) {
      const int chunk = (kk >> 3) + q4;
      bf16x8 af[4], bfr[4];
#pragma unroll
      for (int i = 0; i < 4; ++i)
        af[i] = *(const bf16x8*)&Ald[(chunk * 128 + wm + i * 16 + c) * 8];
#pragma unroll
      for (int j = 0; j < 4; ++j)
        bfr[j] = *(const bf16x8*)&Bld[(chunk * 128 + wn + j * 16 + c) * 8];
#pragma unroll
      for (int i = 0; i < 4; ++i)
#pragma unroll
        for (int j = 0; j < 4; ++j)
          acc[i][j] = MFMA16(af[i], bfr[j], acc[i][j]);
    }
    __syncthreads();  // all reads done before next stage overwrites
  }

  // epilogue: scatter into q/k ([b,h,s,d]) or v-transposed ([b,h,d,s])
#pragma unroll
  for (int i = 0; i < 4; ++i) {
    const int row_base = m0 + wm + i * 16 + q4 * 4;  // 4 consecutive rows rr
    const int b = row_base >> 11, s0 = row_base & 2047;
#pragma unroll
    for (int j = 0; j < 4; ++j) {
      const int colg = n0 + wn + j * 16 + c;
      const int t = colg >> 11, cw = colg & 2047;
      const int h = cw >> 7, d = cw & 127;
      if (t == 2) {
        bf16x4 pv;
        pv[0] = f2bf(acc[i][j][0]); pv[1] = f2bf(acc[i][j][1]);
        pv[2] = f2bf(acc[i][j][2]); pv[3] = f2bf(acc[i][j][3]);
        size_t idx = (((size_t)(b * Hq + h) * Dq + d) * Sq + s0);
        *(bf16x4*)&vtws[idx] = pv;
      } else {
        bf16* dst = (t == 0) ? qws : kws;
        size_t base = ((size_t)(b * Hq + h) * Sq + s0) * Dq + d;
#pragma unroll
        for (int rr = 0; rr < 4; ++rr)
          dst[base + (size_t)rr * Dq] = f2bf(acc[i][j][rr]);
      }
    }
  }
}

// ---------------------------------------------------------------------------
// Kernel 2: in-place RoPE on q,k  [b,h,s,d] bf16, bf16x8 vectorized
// ---------------------------------------------------------------------------
__global__ __launch_bounds__(256) void rope_kernel(bf16* __restrict__ qws,
                                                   bf16* __restrict__ kws) {
  const int idx = blockIdx.x * 256 + threadIdx.x;  // 2 * 65536 rows * 8
  const int t = idx >> 19;
  const int r = idx & ((1 << 19) - 1);
  const int jc = r & 7;
  const int bhs = r >> 3;
  const int s = bhs & (Sq - 1);
  bf16* p = (t ? kws : qws) + (size_t)bhs * Dq;
  bf16x8 lo = *(const bf16x8*)&p[jc * 8];
  bf16x8 hi = *(const bf16x8*)&p[64 + jc * 8];
  bf16x8 olo, ohi;
#pragma unroll
  for (int i = 0; i < 8; ++i) {
    const int j = jc * 8 + i;
    const float freq = __expf(-(float)j * 0.14391157f);
    const float ang = (float)s * freq;
    float sv, cv;
    __sincosf(ang, &sv, &cv);
    const float x1 = bf2f(lo[i]), x2 = bf2f(hi[i]);
    olo[i] = f2bf(x1 * cv - x2 * sv);
    ohi[i] = f2bf(x2 * cv + x1 * sv);
  }
  *(bf16x8*)&p[jc * 8] = olo;
  *(bf16x8*)&p[64 + jc * 8] = ohi;
}

// ---------------------------------------------------------------------------
// Kernel 3: flash attention. Block = (qb, h, b), 256 thr = 4 waves.
// ---------------------------------------------------------------------------
__global__ __launch_bounds__(256) void attn_kernel(
    const bf16* __restrict__ qws, const bf16* __restrict__ kws,
    const bf16* __restrict__ vtws, float* __restrict__ out) {
  __shared__ __align__(16) bf16 Plds[4][32][136];

  const int tid = threadIdx.x, lane = tid & 63, wave = tid >> 6;
  const int q4 = lane >> 4, c = lane & 15;
  const int qb = blockIdx.x, h = blockIdx.y, b = blockIdx.z;
  const size_t bh = (size_t)(b * Hq + h);
  const bf16* qbase = qws + bh * Sq * Dq;
  const bf16* kbase = kws + bh * Sq * Dq;
  const bf16* vbase = vtws + bh * Dq * Sq;
  const int wq = wave * 32;
  const float scale = 0.08838834764831845f;  // 1/sqrt(128)

  bf16x8 qf[2][4];
#pragma unroll
  for (int i = 0; i < 2; ++i)
#pragma unroll
    for (int ks = 0; ks < 4; ++ks)
      qf[i][ks] = *(const bf16x8*)
          &qbase[(size_t)(qb * 128 + wq + i * 16 + c) * Dq + ks * 32 + q4 * 8];

  f32x4 O[2][8];
  float m_i[2][4], l_i[2][4];
#pragma unroll
  for (int i = 0; i < 2; ++i) {
#pragma unroll
    for (int j = 0; j < 8; ++j) O[i][j] = {0.f, 0.f, 0.f, 0.f};
#pragma unroll
    for (int rr = 0; rr < 4; ++rr) { m_i[i][rr] = -1e30f; l_i[i][rr] = 0.f; }
  }

  for (int kb = 0; kb <= qb; ++kb) {
    f32x4 sc[2][8];
#pragma unroll
    for (int i = 0; i < 2; ++i)
#pragma unroll
      for (int j = 0; j < 8; ++j) sc[i][j] = {0.f, 0.f, 0.f, 0.f};
    const bf16* kchunk = kbase + (size_t)kb * 128 * Dq;
#pragma unroll
    for (int ks = 0; ks < 4; ++ks) {
#pragma unroll
      for (int j = 0; j < 8; ++j) {
        bf16x8 bk = *(const bf16x8*)
            &kchunk[(size_t)(j * 16 + c) * Dq + ks * 32 + q4 * 8];
        sc[0][j] = MFMA16(qf[0][ks], bk, sc[0][j]);
        sc[1][j] = MFMA16(qf[1][ks], bk, sc[1][j]);
      }
    }
    const bool diag = (kb == qb);
#pragma unroll
    for (int i = 0; i < 2; ++i) {
#pragma unroll
      for (int rr = 0; rr < 4; ++rr) {
        const int lq = wq + i * 16 + q4 * 4 + rr;
        float m = -1e30f;
#pragma unroll
        for (int j = 0; j < 8; ++j) {
          float v = sc[i][j][rr] * scale;
          if (diag && (j * 16 + c) > lq) v = -1e30f;
          sc[i][j][rr] = v;
          m = fmaxf(m, v);
        }
        m = rowmax16(m);
        const float mn = fmaxf(m_i[i][rr], m);
        const float alpha = __expf(m_i[i][rr] - mn);
        m_i[i][rr] = mn;
        float s = 0.f;
#pragma unroll
        for (int j = 0; j < 8; ++j) {
          float p = __expf(sc[i][j][rr] - mn);
          sc[i][j][rr] = p;
          s += p;
        }
        s = rowsum16(s);
        l_i[i][rr] = l_i[i][rr] * alpha + s;
#pragma unroll
        for (int jd = 0; jd < 8; ++jd) O[i][jd][rr] *= alpha;
      }
    }
#pragma unroll
    for (int i = 0; i < 2; ++i)
#pragma unroll
      for (int j = 0; j < 8; ++j)
#pragma unroll
        for (int rr = 0; rr < 4; ++rr)
          Plds[wave][i * 16 + q4 * 4 + rr][j * 16 + c] = f2bf(sc[i][j][rr]);
    __syncthreads();
#pragma unroll
    for (int j2 = 0; j2 < 4; ++j2) {
      bf16x8 ap0 = *(const bf16x8*)&Plds[wave][c][j2 * 32 + q4 * 8];
      bf16x8 ap1 = *(const bf16x8*)&Plds[wave][16 + c][j2 * 32 + q4 * 8];
#pragma unroll
      for (int j = 0; j < 8; ++j) {
        bf16x8 bv = *(const bf16x8*)
            &vbase[(size_t)(j * 16 + c) * Sq + kb * 128 + j2 * 32 + q4 * 8];
        O[0][j] = MFMA16(ap0, bv, O[0][j]);
        O[1][j] = MFMA16(ap1, bv, O[1][j]);
      }
    }
    __syncthreads();
  }

#pragma unroll
  for (int i = 0; i < 2; ++i)
#pragma unroll
    for (int rr = 0; rr < 4; ++rr) {
      const float inv = 1.0f / l_i[i][rr];
      const int s = qb * 128 + wq + i * 16 + q4 * 4 + rr;
      float* orow = out + ((size_t)b * Sq + s) * Eq + h * Dq;
#pragma unroll
      for (int j = 0; j < 8; ++j) orow[j * 16 + c] = O[i][j][rr] * inv;
    }
}

// ---------------------------------------------------------------------------
extern "C" void kernel_launch(void* const* d_in, const int* in_sizes, int n_in,
                              void* d_out, int out_size, void* d_ws,
                              size_t ws_size, hipStream_t stream) {
  const float* x = (const float*)d_in[0];
  // d_in[1] = mask (causal tril) — implemented analytically, not read.
  const float* w = (const float*)d_in[2];
  float* out = (float*)d_out;

  const size_t nX = (size_t)Bq * Sq * Eq;   // 8,388,608
  const size_t nW = (size_t)Eq * N3E;       // 12,582,912
  const size_t perT = (size_t)Bq * Hq * Sq * Dq;  // 8,388,608

  bf16* xb = (bf16*)d_ws;
  bf16* wt = xb + nX;
  bf16* qws = wt + nW;
  bf16* kws = qws + perT;
  bf16* vtws = kws + perT;

  convert_x<<<nX / (256 * 8), 256, 0, stream>>>(x, xb);
  convert_wt<<<(Eq / 64) * (N3E / 64), 256, 0, stream>>>(w, wt);

  dim3 g1(N3E / 128, (Bq * Sq) / 128);  // 48 x 32
  gemm_qkv<<<g1, 256, 0, stream>>>(xb, wt, qws, kws, vtws);

  rope_kernel<<<(2u * Bq * Hq * Sq * 8) / 256, 256, 0, stream>>>(qws, kws);

  dim3 g3(Sq / 128, Hq, Bq);  // 16 x 16 x 2
  attn_kernel<<<g3, 256, 0, stream>>>(qws, kws, vtws, out);
}